// Round 2
// baseline (1991.046 us; speedup 1.0000x reference)
//
#include <hip/hip_runtime.h>
#include <hip/hip_bf16.h>

// ============================================================================
// ScaledDotProductAttention  B=4 H=16 S=2048 D=64, fp32 in/out.
// d_out = out[B,H,S,D] (32 MiB) ++ attn[B,H,S,S] (1.0 GiB)  -> memory-bound.
// bf16 MFMA for QK^T and PV (no fp32 MFMA on CDNA4); fp32 softmax.
// Block = one (head, 16-row q-tile): grid (128, 64), 512 thr (8 waves),
// 128 KiB LDS score buffer with chunk-XOR swizzle (chunk ^= row) so the
// MFMA D-writes, row-linear softmax sweeps, and PV fragment reads are all
// conflict-free / 2-way.
// ============================================================================

#define NB 4
#define NH 16
#define S_ 2048
#define D_ 64
#define QT 16
#define NW 8
#define NT 512
#define KSEG (S_ / NW)            // 256 k-columns per wave
#define SCALE 0.125f              // 1/sqrt(64)
#define MASKFILL -1000000000.0f

typedef float f32x4 __attribute__((ext_vector_type(4)));
typedef int   i32x4 __attribute__((ext_vector_type(4)));
typedef short bf16x8 __attribute__((ext_vector_type(8)));

__device__ __forceinline__ short f2bf(float x) {
  union { __hip_bfloat16 h; short s; } u;
  u.h = __float2bfloat16(x);
  return u.s;
}

__global__ __launch_bounds__(NT, 2)
void sdpa_fused(const float* __restrict__ q, const float* __restrict__ k,
                const float* __restrict__ v, const int* __restrict__ mask,
                float* __restrict__ out, float* __restrict__ attn)
{
  __shared__ float sc[QT * S_];   // 128 KiB: scores -> probs -> (reused) partial-out

  const int qt   = blockIdx.x;    // q-tile   [0,128)
  const int bh   = blockIdx.y;    // b*16+h   [0,64)
  const int b    = bh >> 4;
  const int tid  = threadIdx.x;
  const int wid  = tid >> 6;
  const int lane = tid & 63;
  const int l15  = lane & 15;
  const int l4   = lane >> 4;     // 0..3

  const float* __restrict__ qh = q + (size_t)bh * S_ * D_;
  const float* __restrict__ kh = k + (size_t)bh * S_ * D_;
  const float* __restrict__ vh = v + (size_t)bh * S_ * D_;
  const int*   __restrict__ mb = mask + (size_t)b * S_ * S_;
  const int q0 = qt * QT;

  // ---- Q A-fragments (16q x 64d, pre-scaled), identical in every wave ----
  // A frag layout (16x16x32): lane holds A[row=l15][k=(l>>4)*8+j], j=0..7.
  bf16x8 aq[2];
  {
    const float* qrow = qh + (size_t)(q0 + l15) * D_ + l4 * 8;
    #pragma unroll
    for (int h = 0; h < 2; ++h) {
      f32x4 x0 = *(const f32x4*)(qrow + h * 32);
      f32x4 x1 = *(const f32x4*)(qrow + h * 32 + 4);
      bf16x8 a;
      #pragma unroll
      for (int j = 0; j < 4; ++j) {
        a[j]     = f2bf(x0[j] * SCALE);
        a[j + 4] = f2bf(x1[j] * SCALE);
      }
      aq[h] = a;
    }
  }

  // ---- QK^T: wave w computes score columns [256w, 256w+256), all 16 rows --
  const int kbase = wid * KSEG;
  #pragma unroll 2
  for (int g = 0; g < KSEG / 16; ++g) {
    const int kc = kbase + g * 16;
    // B frag: B[d][n]=K[kc+n][d]; lane holds col n=l15, d=(l>>4)*8+j (contig)
    const float* krow = kh + (size_t)(kc + l15) * D_ + l4 * 8;
    f32x4 acc = {0.f, 0.f, 0.f, 0.f};
    #pragma unroll
    for (int h = 0; h < 2; ++h) {
      f32x4 x0 = *(const f32x4*)(krow + h * 32);
      f32x4 x1 = *(const f32x4*)(krow + h * 32 + 4);
      bf16x8 bk;
      #pragma unroll
      for (int j = 0; j < 4; ++j) { bk[j] = f2bf(x0[j]); bk[j + 4] = f2bf(x1[j]); }
      acc = __builtin_amdgcn_mfma_f32_16x16x32_bf16(aq[h], bk, acc, 0, 0, 0);
    }
    // D layout: row=(l>>4)*4+reg, col=l15 (m89-verified). Swizzled LDS write.
    #pragma unroll
    for (int r = 0; r < 4; ++r) {
      const int row = l4 * 4 + r;
      const int col = kc + l15;
      sc[row * S_ + ((((col >> 2) ^ row) << 2) | (col & 3))] = acc[r];
    }
  }
  __syncthreads();

  // ---- softmax: wave w owns rows {2w, 2w+1}; mask folded into pass 1 ----
  #pragma unroll
  for (int rr = 0; rr < 2; ++rr) {
    const int row = wid * 2 + rr;
    float* srow = sc + row * S_;
    const int* mrow = mb + (size_t)(q0 + row) * S_;

    // pass 1: apply mask, row max
    f32x4 m4 = {-3.0e38f, -3.0e38f, -3.0e38f, -3.0e38f};
    for (int i = 0; i < 8; ++i) {
      const int clin = i * 64 + lane;          // linear float4-chunk id
      const int c = (clin ^ row) << 2;         // swizzled float offset
      f32x4 vv = *(f32x4*)(srow + c);
      i32x4 mm = *(const i32x4*)(mrow + clin * 4);
      #pragma unroll
      for (int j = 0; j < 4; ++j) {
        vv[j] = mm[j] ? vv[j] : MASKFILL;
        m4[j] = fmaxf(m4[j], vv[j]);
      }
      *(f32x4*)(srow + c) = vv;
    }
    float mx = fmaxf(fmaxf(m4[0], m4[1]), fmaxf(m4[2], m4[3]));
    #pragma unroll
    for (int off = 32; off >= 1; off >>= 1) mx = fmaxf(mx, __shfl_xor(mx, off));

    // pass 2: exp + row sum
    f32x4 s4 = {0.f, 0.f, 0.f, 0.f};
    for (int i = 0; i < 8; ++i) {
      const int c = ((i * 64 + lane) ^ row) << 2;
      f32x4 vv = *(f32x4*)(srow + c);
      f32x4 e;
      #pragma unroll
      for (int j = 0; j < 4; ++j) { e[j] = __expf(vv[j] - mx); s4[j] += e[j]; }
      *(f32x4*)(srow + c) = e;
    }
    float sm = s4[0] + s4[1] + s4[2] + s4[3];
    #pragma unroll
    for (int off = 32; off >= 1; off >>= 1) sm += __shfl_xor(sm, off);
    const float rinv = 1.0f / sm;

    // pass 3: normalize in LDS + coalesced float4 store of attn row
    float* arow = attn + ((size_t)bh * S_ + q0 + row) * S_;
    for (int i = 0; i < 8; ++i) {
      const int clin = i * 64 + lane;
      const int c = (clin ^ row) << 2;
      f32x4 vv = *(f32x4*)(srow + c);
      vv *= rinv;
      *(f32x4*)(srow + c) = vv;
      *(f32x4*)(arow + clin * 4) = vv;
    }
  }
  __syncthreads();

  // ---- PV: wave w covers k in [256w, 256w+256); partial out in regs ----
  f32x4 oacc[4] = {{0,0,0,0},{0,0,0,0},{0,0,0,0},{0,0,0,0}};
  #pragma unroll 2
  for (int ks = 0; ks < KSEG; ks += 32) {
    const int k0 = kbase + ks + l4 * 8;        // this lane's 8 k's (contig)
    // A frag: P[q=l15][k0..k0+7] from swizzled LDS (two 16B chunks)
    const float* srow = sc + l15 * S_;
    const int cc = k0 >> 2;                    // even
    f32x4 p0 = *(const f32x4*)(srow + ((cc ^ l15) << 2));
    f32x4 p1 = *(const f32x4*)(srow + (((cc + 1) ^ l15) << 2));
    bf16x8 ap;
    #pragma unroll
    for (int j = 0; j < 4; ++j) { ap[j] = f2bf(p0[j]); ap[j + 4] = f2bf(p1[j]); }
    #pragma unroll
    for (int g = 0; g < 4; ++g) {
      // B frag: V[k][dv]; col dv = g*16+l15, k = k0+j (strided dword loads,
      // each instruction coalesces to 4x64B lines, V is L2-resident)
      bf16x8 bv;
      #pragma unroll
      for (int j = 0; j < 8; ++j)
        bv[j] = f2bf(vh[(size_t)(k0 + j) * D_ + g * 16 + l15]);
      oacc[g] = __builtin_amdgcn_mfma_f32_16x16x32_bf16(ap, bv, oacc[g], 0, 0, 0);
    }
  }
  __syncthreads();  // everyone done reading probs from sc

  // cross-wave reduction of partial out through (reused) sc
  float* part = sc;                            // 8 * 16 * 64 fp32 = 32 KiB
  #pragma unroll
  for (int g = 0; g < 4; ++g) {
    #pragma unroll
    for (int r = 0; r < 4; ++r)
      part[(wid * QT + l4 * 4 + r) * D_ + g * 16 + l15] = oacc[g][r];
  }
  __syncthreads();

  float* orow = out + ((size_t)bh * S_ + q0) * D_;
  for (int o = tid; o < QT * D_; o += NT) {
    float s = 0.f;
    #pragma unroll
    for (int w = 0; w < NW; ++w) s += part[w * (QT * D_) + o];
    orow[o] = s;
  }
}

extern "C" void kernel_launch(void* const* d_in, const int* in_sizes, int n_in,
                              void* d_out, int out_size, void* d_ws, size_t ws_size,
                              hipStream_t stream) {
  const float* q    = (const float*)d_in[0];
  const float* k    = (const float*)d_in[1];
  const float* v    = (const float*)d_in[2];
  const int*   mask = (const int*)d_in[3];
  float* out  = (float*)d_out;
  float* attn = out + (size_t)NB * NH * S_ * D_;   // out is 8,388,608 floats
  dim3 grid(S_ / QT, NB * NH);
  sdpa_fused<<<grid, dim3(NT), 0, stream>>>(q, k, v, mask, out, attn);
}

// Round 3
// 1734.049 us; speedup vs baseline: 1.1482x; 1.1482x over previous
//
#include <hip/hip_runtime.h>
#include <hip/hip_bf16.h>

// ============================================================================
// ScaledDotProductAttention  B=4 H=16 S=2048 D=64, fp32 in/out.
// d_out = out[B,H,S,D] (32 MiB) ++ attn[B,H,S,S] (1.0 GiB).
// Round-2 counters: MfmaUtil 2.6 / VALU 15 / HBM 19% / Occ 24% -> latency-
// bound, 1 block/CU (128 KiB LDS) + serial softmax LDS sweeps.
// This version: register-resident scores (wave owns 16x256 tile = 64 f32/lane),
// softmax stats via shfl + tiny LDS combine, bf16-packed probs in regs,
// attn stored straight from regs (nontemporal), PV A-frags via 2 KiB XOR-
// swizzled per-wave LDS bounce (double-buffered). LDS 128K -> 34K,
// launch_bounds(512,4) -> 2 blocks/CU. XCD-bijective block swizzle.
// ============================================================================

#define NB 4
#define NH 16
#define S_ 2048
#define D_ 64
#define QT 16
#define NW 8
#define NT 512
#define KSEG 256          // k-columns per wave
#define NF 16             // 16-col frags per wave
#define SCALE 0.125f      // 1/sqrt(64)
#define MASKFILL -1000000000.0f

typedef float f32x4 __attribute__((ext_vector_type(4)));
typedef short bf16x8 __attribute__((ext_vector_type(8)));

__device__ __forceinline__ short f2bf(float x) {
  union { __hip_bfloat16 h; short s; } u;
  u.h = __float2bfloat16(x);
  return u.s;
}
__device__ __forceinline__ unsigned pack2(float a, float b) {
  return (unsigned)(unsigned short)f2bf(a) | ((unsigned)(unsigned short)f2bf(b) << 16);
}
__device__ __forceinline__ float unlo(unsigned u) { return __uint_as_float(u << 16); }
__device__ __forceinline__ float unhi(unsigned u) { return __uint_as_float(u & 0xffff0000u); }

// rule-18-hardened wave-local LDS write->read fence
__device__ __forceinline__ void lds_fence() {
  __builtin_amdgcn_sched_barrier(0);
  asm volatile("s_waitcnt lgkmcnt(0)" ::: "memory");
  __builtin_amdgcn_sched_barrier(0);
}

__global__ __launch_bounds__(NT, 4)
void sdpa_fused(const float* __restrict__ q, const float* __restrict__ k,
                const float* __restrict__ v, const int* __restrict__ mask,
                float* __restrict__ out, float* __restrict__ attn)
{
  // 32 KiB bounce buffers (per-wave 2x[16][32] fp32, XOR-swizzled), later
  // overlaid as the 8x16x64 partial-out reduction buffer. +1 KiB stats.
  __shared__ float tb[NW][2][QT][32];
  __shared__ float mbuf[NW][QT];
  __shared__ float lbuf[NW][QT];

  // XCD-bijective swizzle: 8192 blocks = 8 XCDs x 1024. XCD x gets swz range
  // [x*1024,(x+1)*1024) = q-tiles 0..127 of heads 8x..8x+7 (same batch b ->
  // K/V and mask L2/L3 locality per XCD).
  const int bid = blockIdx.x;
  const int swz = (bid & 7) * 1024 + (bid >> 3);
  const int qt  = swz & 127;
  const int bh  = swz >> 7;
  const int b   = bh >> 4;

  const int tid  = threadIdx.x;
  const int wid  = tid >> 6;
  const int lane = tid & 63;
  const int l15  = lane & 15;
  const int l4   = lane >> 4;          // 0..3

  const float* __restrict__ qh = q + (size_t)bh * S_ * D_;
  const float* __restrict__ kh = k + (size_t)bh * S_ * D_;
  const float* __restrict__ vh = v + (size_t)bh * S_ * D_;
  const int*   __restrict__ mb = mask + (size_t)b * S_ * S_;
  const int q0    = qt * QT;
  const int kbase = wid * KSEG;

  // ---- Q A-frags (pre-scaled). A layout: lane holds A[row=l15][k=l4*8+j]. --
  bf16x8 aq[2];
  {
    const float* qrow = qh + (size_t)(q0 + l15) * D_ + l4 * 8;
    #pragma unroll
    for (int h = 0; h < 2; ++h) {
      f32x4 x0 = *(const f32x4*)(qrow + h * 32);
      f32x4 x1 = *(const f32x4*)(qrow + h * 32 + 4);
      bf16x8 a;
      #pragma unroll
      for (int j = 0; j < 4; ++j) {
        a[j]     = f2bf(x0[j] * SCALE);
        a[j + 4] = f2bf(x1[j] * SCALE);
      }
      aq[h] = a;
    }
  }

  // ---- QK^T: 16 D-frags in regs. D layout: row=l4*4+r, col=l15. ----------
  f32x4 acc[NF];
  {
    const float* krow = kh + (size_t)(kbase + l15) * D_ + l4 * 8;
    #pragma unroll
    for (int f = 0; f < NF; ++f) {
      f32x4 a0 = {0.f, 0.f, 0.f, 0.f};
      #pragma unroll
      for (int h = 0; h < 2; ++h) {
        f32x4 x0 = *(const f32x4*)(krow + h * 32);
        f32x4 x1 = *(const f32x4*)(krow + h * 32 + 4);
        bf16x8 bk;
        #pragma unroll
        for (int j = 0; j < 4; ++j) { bk[j] = f2bf(x0[j]); bk[j + 4] = f2bf(x1[j]); }
        a0 = __builtin_amdgcn_mfma_f32_16x16x32_bf16(aq[h], bk, a0, 0, 0, 0);
      }
      acc[f] = a0;
      krow += 16 * D_;
    }
  }

  // ---- mask + row max (all in regs) --------------------------------------
  const int* mr0 = mb + (size_t)(q0 + l4 * 4 + 0) * S_ + kbase + l15;
  const int* mr1 = mr0 + S_;
  const int* mr2 = mr1 + S_;
  const int* mr3 = mr2 + S_;
  float rmax[4] = {-3.0e38f, -3.0e38f, -3.0e38f, -3.0e38f};
  #pragma unroll
  for (int f = 0; f < NF; ++f) {
    const int o = f * 16;
    float s0 = mr0[o] ? acc[f][0] : MASKFILL;
    float s1 = mr1[o] ? acc[f][1] : MASKFILL;
    float s2 = mr2[o] ? acc[f][2] : MASKFILL;
    float s3 = mr3[o] ? acc[f][3] : MASKFILL;
    acc[f][0] = s0; acc[f][1] = s1; acc[f][2] = s2; acc[f][3] = s3;
    rmax[0] = fmaxf(rmax[0], s0); rmax[1] = fmaxf(rmax[1], s1);
    rmax[2] = fmaxf(rmax[2], s2); rmax[3] = fmaxf(rmax[3], s3);
  }
  #pragma unroll
  for (int off = 1; off < 16; off <<= 1) {
    #pragma unroll
    for (int r = 0; r < 4; ++r) rmax[r] = fmaxf(rmax[r], __shfl_xor(rmax[r], off));
  }
  {
    float wv = (l15 == 0) ? rmax[0] : (l15 == 1) ? rmax[1] : (l15 == 2) ? rmax[2] : rmax[3];
    if (l15 < 4) mbuf[wid][l4 * 4 + l15] = wv;
  }
  __syncthreads();
  float M[4];
  {
    f32x4 mv = *(const f32x4*)&mbuf[0][l4 * 4];
    #pragma unroll
    for (int w = 1; w < NW; ++w) {
      f32x4 t = *(const f32x4*)&mbuf[w][l4 * 4];
      #pragma unroll
      for (int r = 0; r < 4; ++r) mv[r] = fmaxf(mv[r], t[r]);
    }
    #pragma unroll
    for (int r = 0; r < 4; ++r) M[r] = mv[r];
  }

  // ---- exp (fp32) + row sum + pack probs to bf16 in regs -----------------
  float rsum[4] = {0.f, 0.f, 0.f, 0.f};
  uint2 pk[NF];
  #pragma unroll
  for (int f = 0; f < NF; ++f) {
    float e0 = __expf(acc[f][0] - M[0]);
    float e1 = __expf(acc[f][1] - M[1]);
    float e2 = __expf(acc[f][2] - M[2]);
    float e3 = __expf(acc[f][3] - M[3]);
    rsum[0] += e0; rsum[1] += e1; rsum[2] += e2; rsum[3] += e3;
    pk[f].x = pack2(e0, e1);
    pk[f].y = pack2(e2, e3);
  }
  #pragma unroll
  for (int off = 1; off < 16; off <<= 1) {
    #pragma unroll
    for (int r = 0; r < 4; ++r) rsum[r] += __shfl_xor(rsum[r], off);
  }
  {
    float wv = (l15 == 0) ? rsum[0] : (l15 == 1) ? rsum[1] : (l15 == 2) ? rsum[2] : rsum[3];
    if (l15 < 4) lbuf[wid][l4 * 4 + l15] = wv;
  }
  __syncthreads();
  float rinv[4];
  {
    f32x4 lv = *(const f32x4*)&lbuf[0][l4 * 4];
    #pragma unroll
    for (int w = 1; w < NW; ++w) {
      f32x4 t = *(const f32x4*)&lbuf[w][l4 * 4];
      #pragma unroll
      for (int r = 0; r < 4; ++r) lv[r] += t[r];
    }
    #pragma unroll
    for (int r = 0; r < 4; ++r) rinv[r] = 1.0f / lv[r];
  }

  // ---- attn store: straight from regs, nontemporal (write-once stream) ---
  {
    float* ar0 = attn + ((size_t)bh * S_ + q0 + l4 * 4) * S_ + kbase + l15;
    float* ar1 = ar0 + S_;
    float* ar2 = ar1 + S_;
    float* ar3 = ar2 + S_;
    #pragma unroll
    for (int f = 0; f < NF; ++f) {
      const int o = f * 16;
      __builtin_nontemporal_store(unlo(pk[f].x) * rinv[0], ar0 + o);
      __builtin_nontemporal_store(unhi(pk[f].x) * rinv[1], ar1 + o);
      __builtin_nontemporal_store(unlo(pk[f].y) * rinv[2], ar2 + o);
      __builtin_nontemporal_store(unhi(pk[f].y) * rinv[3], ar3 + o);
    }
  }

  // ---- PV: per 32-col chunk, bounce probs through XOR-swizzled LDS -------
  // write: tb[w][pc][row][col ^ ((row&7)<<2)]  (2-way max = free)
  // read : lane(q=l15,l4) b128 at [q][(l4*8 {+4}) ^ ((q&7)<<2)] (2-way max)
  f32x4 oacc[4] = {{0,0,0,0},{0,0,0,0},{0,0,0,0},{0,0,0,0}};
  const float* vb = vh + (size_t)kbase * D_ + l15;
  #pragma unroll
  for (int c = 0; c < 8; ++c) {
    const int pc = c & 1;
    #pragma unroll
    for (int fr = 0; fr < 2; ++fr) {
      const int f = 2 * c + fr;
      #pragma unroll
      for (int r = 0; r < 4; ++r) {
        const int row = l4 * 4 + r;
        const int col = fr * 16 + l15;
        const float pv_ =
            ((r == 0) ? unlo(pk[f].x) : (r == 1) ? unhi(pk[f].x)
             : (r == 2) ? unlo(pk[f].y) : unhi(pk[f].y)) * rinv[r];
        tb[wid][pc][row][col ^ ((row & 7) << 2)] = pv_;
      }
    }
    lds_fence();
    const int swzr = (l15 & 7) << 2;
    const float* tbp = &tb[wid][pc][l15][0];
    f32x4 p0 = *(const f32x4*)(tbp + ((l4 * 8)     ^ swzr));
    f32x4 p1 = *(const f32x4*)(tbp + ((l4 * 8 + 4) ^ swzr));
    bf16x8 ap;
    #pragma unroll
    for (int j = 0; j < 4; ++j) { ap[j] = f2bf(p0[j]); ap[j + 4] = f2bf(p1[j]); }
    const float* vc = vb + (size_t)(c * 32 + l4 * 8) * D_;
    #pragma unroll
    for (int g = 0; g < 4; ++g) {
      bf16x8 bv;
      #pragma unroll
      for (int j = 0; j < 8; ++j) bv[j] = f2bf(vc[j * D_ + g * 16]);
      oacc[g] = __builtin_amdgcn_mfma_f32_16x16x32_bf16(ap, bv, oacc[g], 0, 0, 0);
    }
  }

  // ---- cross-wave out reduction: overlay partials on tb (wave-private) ---
  lds_fence();
  {
    float* pw = &tb[0][0][0][0] + wid * (QT * D_);
    #pragma unroll
    for (int g = 0; g < 4; ++g) {
      #pragma unroll
      for (int r = 0; r < 4; ++r)
        pw[(l4 * 4 + r) * D_ + g * 16 + l15] = oacc[g][r];
    }
  }
  __syncthreads();
  {
    const float* pr = &tb[0][0][0][0];
    float* orow = out + ((size_t)bh * S_ + q0) * D_;
    for (int o = tid; o < QT * D_; o += NT) {
      float s = 0.f;
      #pragma unroll
      for (int w = 0; w < NW; ++w) s += pr[w * (QT * D_) + o];
      __builtin_nontemporal_store(s, orow + o);
    }
  }
}

extern "C" void kernel_launch(void* const* d_in, const int* in_sizes, int n_in,
                              void* d_out, int out_size, void* d_ws, size_t ws_size,
                              hipStream_t stream) {
  const float* q    = (const float*)d_in[0];
  const float* k    = (const float*)d_in[1];
  const float* v    = (const float*)d_in[2];
  const int*   mask = (const int*)d_in[3];
  float* out  = (float*)d_out;
  float* attn = out + (size_t)NB * NH * S_ * D_;
  sdpa_fused<<<dim3(S_ / QT * NB * NH), dim3(NT), 0, stream>>>(q, k, v, mask, out, attn);
}